// Round 8
// baseline (479.233 us; speedup 1.0000x reference)
//
#include <hip/hip_runtime.h>
#include <hip/hip_bf16.h>
#include <math.h>

#define N_NODES 100000
#define N_EDGES 3200000
#define NFEAT 128
#define NHID 128
#define NCLASS 8
#define BN_EPS 1e-5f
#define NBC 391            // coarse buckets of 256 nodes
#define PART_BLOCKS 782    // ceil(N_EDGES / 4096)
#define WT_BLOCKS 64       // 16384 W elements / 256
#define PSTRIDE_U ((N_NODES + 16) * 16)   // ushorts per feature plane (16 feats/node + zero row)

typedef __attribute__((ext_vector_type(8))) short short8;
typedef __attribute__((ext_vector_type(4))) float f32x4;

__device__ __forceinline__ short f2bf(float f) {
    __hip_bfloat16 b = __float2bfloat16(f);   // RNE
    return *reinterpret_cast<short*>(&b);
}
__device__ __forceinline__ float bf_lo(unsigned u) { return __uint_as_float(u << 16); }
__device__ __forceinline__ float bf_hi(unsigned u) { return __uint_as_float(u & 0xffff0000u); }

// ---------------- coarse histogram (+ fused Wt convert & plane zero-rows) ----------------

__global__ __launch_bounds__(256) void k_chist(const int* __restrict__ dst,
                                               int* __restrict__ ghist,
                                               const float* __restrict__ W,
                                               unsigned short* __restrict__ Wt,
                                               unsigned short* __restrict__ hbS) {
    if (blockIdx.x >= PART_BLOCKS) {
        int idx = (blockIdx.x - PART_BLOCKS) * 256 + threadIdx.x;
        if (idx < 128) {   // zero row of each plane: 8 planes x 16 ushorts
            int s = idx >> 4, e = idx & 15;
            hbS[(size_t)s * PSTRIDE_U + (size_t)N_NODES * 16 + e] = 0;
        }
        int k = idx >> 7, n = idx & 127;
        Wt[n * NFEAT + k] = (unsigned short)f2bf(W[idx]);
        return;
    }
    __shared__ int lh[NBC];
    const int tid = threadIdx.x;
    for (int i = tid; i < NBC; i += 256) lh[i] = 0;
    __syncthreads();
    const int4* dst4 = (const int4*)dst;
    const int q0 = blockIdx.x * 1024 + tid;
#pragma unroll
    for (int i = 0; i < 4; ++i) {
        int q = q0 + i * 256;
        if (q < N_EDGES / 4) {
            int4 d = dst4[q];
            atomicAdd(&lh[d.x >> 8], 1);
            atomicAdd(&lh[d.y >> 8], 1);
            atomicAdd(&lh[d.z >> 8], 1);
            atomicAdd(&lh[d.w >> 8], 1);
        }
    }
    __syncthreads();
    for (int i = tid; i < NBC; i += 256) {
        int c = lh[i];
        if (c) atomicAdd(&ghist[i], c);
    }
}

// scan coarse hist; also zero BN stats + ticket (used much later by k_stats)
__global__ __launch_bounds__(512) void k_cscan(const int* __restrict__ ghist,
                                               int* __restrict__ coff,
                                               int* __restrict__ ccur,
                                               int* __restrict__ off,
                                               float* __restrict__ stats,
                                               int* __restrict__ ticket) {
    __shared__ int tmp[512];
    const int t = threadIdx.x;
    if (t < 256) stats[t] = 0.f;
    if (t == 0) *ticket = 0;
    int v = (t < NBC) ? ghist[t] : 0;
    tmp[t] = v;
    __syncthreads();
    for (int d = 1; d < 512; d <<= 1) {
        int u = (t >= d) ? tmp[t - d] : 0;
        __syncthreads();
        tmp[t] += u;
        __syncthreads();
    }
    int excl = tmp[t] - v;
    if (t < NBC) {
        coff[t] = excl;
        ccur[t] = excl;
    }
    if (t == NBC - 1) {
        coff[NBC] = tmp[t];
        off[N_NODES] = tmp[t];
    }
}

// scatter packed (src<<8 | dst&255) into coarse regions
__global__ __launch_bounds__(256) void k_part(const int* __restrict__ src,
                                              const int* __restrict__ dst,
                                              int* __restrict__ ccur,
                                              unsigned* __restrict__ epack) {
    __shared__ int lh[NBC];
    __shared__ int lbase[NBC];
    const int tid = threadIdx.x;
    for (int i = tid; i < NBC; i += 256) lh[i] = 0;
    __syncthreads();
    const int4* src4 = (const int4*)src;
    const int4* dst4 = (const int4*)dst;
    const int q0 = blockIdx.x * 1024 + tid;
    int4 sv[4], dv[4];
    int rk[16];
    bool val[4];
#pragma unroll
    for (int i = 0; i < 4; ++i) {
        int q = q0 + i * 256;
        val[i] = q < N_EDGES / 4;
        if (val[i]) {
            sv[i] = src4[q];
            dv[i] = dst4[q];
            rk[i * 4 + 0] = atomicAdd(&lh[dv[i].x >> 8], 1);
            rk[i * 4 + 1] = atomicAdd(&lh[dv[i].y >> 8], 1);
            rk[i * 4 + 2] = atomicAdd(&lh[dv[i].z >> 8], 1);
            rk[i * 4 + 3] = atomicAdd(&lh[dv[i].w >> 8], 1);
        }
    }
    __syncthreads();
    for (int i = tid; i < NBC; i += 256) {
        int c = lh[i];
        lbase[i] = c ? atomicAdd(&ccur[i], c) : 0;
    }
    __syncthreads();
#pragma unroll
    for (int i = 0; i < 4; ++i) {
        if (val[i]) {
            epack[lbase[dv[i].x >> 8] + rk[i * 4 + 0]] = ((unsigned)sv[i].x << 8) | (unsigned)(dv[i].x & 255);
            epack[lbase[dv[i].y >> 8] + rk[i * 4 + 1]] = ((unsigned)sv[i].y << 8) | (unsigned)(dv[i].y & 255);
            epack[lbase[dv[i].z >> 8] + rk[i * 4 + 2]] = ((unsigned)sv[i].z << 8) | (unsigned)(dv[i].z & 255);
            epack[lbase[dv[i].w >> 8] + rk[i * 4 + 3]] = ((unsigned)sv[i].w << 8) | (unsigned)(dv[i].w & 255);
        }
    }
}

// per-coarse-bucket fine sort: exact CSR off/dinv/esrc
__global__ __launch_bounds__(256) void k_fine(const unsigned* __restrict__ epack,
                                              const int* __restrict__ coff,
                                              int* __restrict__ off,
                                              float* __restrict__ dinv,
                                              int* __restrict__ esrc) {
    __shared__ int lh[256], lcur[256], lsc[256];
    const int tid = threadIdx.x;
    const int b = blockIdx.x;
    const int node0 = b << 8;
    const int span = min(256, N_NODES - node0);
    lh[tid] = 0;
    __syncthreads();
    const int lo = coff[b], hiEnd = coff[b + 1];
    for (int i = lo + tid; i < hiEnd; i += 256)
        atomicAdd(&lh[epack[i] & 255u], 1);
    __syncthreads();
    int v = lh[tid];
    lsc[tid] = v;
    __syncthreads();
    for (int d = 1; d < 256; d <<= 1) {
        int u = (tid >= d) ? lsc[tid - d] : 0;
        __syncthreads();
        lsc[tid] += u;
        __syncthreads();
    }
    int excl = lsc[tid] - v;
    lcur[tid] = excl;
    if (tid < span) {
        off[node0 + tid] = lo + excl;
        dinv[node0 + tid] = rsqrtf((float)(v + 1));
    }
    __syncthreads();
    for (int i = lo + tid; i < hiEnd; i += 256) {
        unsigned p = epack[i];
        int pos = atomicAdd(&lcur[p & 255u], 1);
        esrc[lo + pos] = (int)(p >> 8);
    }
}

// ---------------- MFMA GEMM: hbS[c>>4][r][c&15] = bf16(dinv[r] * (x @ W)[r][c]) ----------------

#define WSTRIDE 136
__global__ __launch_bounds__(256) void k_gemm(const float* __restrict__ x,
                                              const unsigned short* __restrict__ Wt,
                                              const float* __restrict__ dinv,
                                              unsigned short* __restrict__ hbS) {
    __shared__ short wlds[NHID * WSTRIDE];
    const int tid = threadIdx.x;

    const unsigned* Wt32 = (const unsigned*)Wt;
    unsigned* wl32 = (unsigned*)wlds;
#pragma unroll
    for (int i = 0; i < 32; ++i) {
        int d = tid + i * 256;
        int n = d >> 6, kp = d & 63;
        wl32[n * (WSTRIDE / 2) + kp] = Wt32[d];
    }
    __syncthreads();

    const int wid = tid >> 6, lane = tid & 63;
    const int qw = lane >> 4, lr = lane & 15;
    const int arow = blockIdx.x * 64 + wid * 16 + lr;
    const bool avalid = arow < N_NODES;

    short8 a[4];
#pragma unroll
    for (int ks = 0; ks < 4; ++ks) {
        if (avalid) {
            const float* p = x + (size_t)arow * NFEAT + ks * 32 + qw * 8;
            float4 v0 = *(const float4*)p;
            float4 v1 = *(const float4*)(p + 4);
            short8 t;
            t[0] = f2bf(v0.x); t[1] = f2bf(v0.y); t[2] = f2bf(v0.z); t[3] = f2bf(v0.w);
            t[4] = f2bf(v1.x); t[5] = f2bf(v1.y); t[6] = f2bf(v1.z); t[7] = f2bf(v1.w);
            a[ks] = t;
        } else {
            short8 t;
#pragma unroll
            for (int j = 0; j < 8; ++j) t[j] = 0;
            a[ks] = t;
        }
    }

    f32x4 acc[8];
#pragma unroll
    for (int nt = 0; nt < 8; ++nt) acc[nt] = (f32x4){0.f, 0.f, 0.f, 0.f};

#pragma unroll
    for (int nt = 0; nt < 8; ++nt) {
#pragma unroll
        for (int ks = 0; ks < 4; ++ks) {
            short8 bfr = *(const short8*)&wlds[(nt * 16 + lr) * WSTRIDE + ks * 32 + qw * 8];
            acc[nt] = __builtin_amdgcn_mfma_f32_16x16x32_bf16(a[ks], bfr, acc[nt], 0, 0, 0);
        }
    }

    const int rbase = blockIdx.x * 64 + wid * 16 + qw * 4;
    float dv[4];
#pragma unroll
    for (int j = 0; j < 4; ++j) dv[j] = (rbase + j < N_NODES) ? dinv[rbase + j] : 0.f;
#pragma unroll
    for (int j = 0; j < 4; ++j) {
        int r = rbase + j;
        if (r >= N_NODES) continue;
#pragma unroll
        for (int nt = 0; nt < 8; ++nt)
            hbS[(size_t)nt * PSTRIDE_U + (size_t)r * 16 + lr] = (unsigned short)f2bf(dv[j] * acc[nt][j]);
    }
}

// ---------------- aggregation: XCD-sliced feature planes ----------------
// grid = 8 slices x 12500 chunks; slice = bid&7 ~ XCD (round-robin mapping).
// Wave = one node; 8 groups x 8 lanes; group g gathers edge 8k+g's 32 B
// plane row (uint/lane). 2-deep unroll; zero-row pads tails.

__global__ __launch_bounds__(512) void k_agg(const int* __restrict__ off,
                                             const int* __restrict__ esrc,
                                             const float* __restrict__ dinv,
                                             const unsigned* __restrict__ hbS32,
                                             float* __restrict__ embed) {
    const int slice = blockIdx.x & 7;
    const int chunk = blockIdx.x >> 3;
    const int wv = threadIdx.x >> 6;       // 0..7
    const int lane = threadIdx.x & 63;
    const int grp = lane >> 3, gl = lane & 7;
    const int node = chunk * 8 + wv;       // N_NODES = 8*12500 exactly

    const unsigned* __restrict__ hp = hbS32 + (size_t)slice * (PSTRIDE_U / 2);

    unsigned u0 = (grp == 0) ? hp[(size_t)node * 8 + gl] : 0u;
    float aAx = bf_lo(u0), aAy = bf_hi(u0);
    float aBx = 0.f, aBy = 0.f;

    const int begin = off[node], end = off[node + 1];
    for (int base = begin; base < end; base += 64) {
        int m = end - base;
        if (m > 64) m = 64;
        int sv = (lane < m) ? __builtin_nontemporal_load(esrc + base + lane) : N_NODES;
        const int kmax = (m + 7) >> 3;
        for (int k = 0; k < kmax; k += 2) {
            int sA = __shfl(sv, 8 * k + grp);
            int sB = __shfl(sv, 8 * k + 8 + grp);   // lanes >= m hold N_NODES (zero row)
            unsigned uA = hp[(size_t)sA * 8 + gl];
            unsigned uB = hp[(size_t)sB * 8 + gl];
            aAx += bf_lo(uA); aAy += bf_hi(uA);
            aBx += bf_lo(uB); aBy += bf_hi(uB);
        }
    }
    float ax = aAx + aBx, ay = aAy + aBy;
#pragma unroll
    for (int d = 8; d < 64; d <<= 1) {
        ax += __shfl_xor(ax, d);
        ay += __shfl_xor(ay, d);
    }
    if (grp == 0) {
        const float dn = dinv[node];
        float* ep = embed + (size_t)node * NHID + slice * 16 + gl * 2;
        __builtin_nontemporal_store(ax * dn, ep);
        __builtin_nontemporal_store(ay * dn, ep + 1);
    }
}

// ---------------- BatchNorm stats + (last block) params ----------------

__global__ __launch_bounds__(256) void k_stats(const float* __restrict__ agg,
                                               float* __restrict__ stats,
                                               int* __restrict__ ticket,
                                               const float* __restrict__ gamma,
                                               const float* __restrict__ beta,
                                               float* __restrict__ ss) {
    const int cb = threadIdx.x & 31;   // float4 col
    const int rg = threadIdx.x >> 5;   // 0..7
    const float4* a4 = (const float4*)agg;
    float4 s = {0.f, 0.f, 0.f, 0.f}, s2 = {0.f, 0.f, 0.f, 0.f};
    for (int r = blockIdx.x * 8 + rg; r < N_NODES; r += gridDim.x * 8) {
        float4 v = a4[(size_t)r * 32 + cb];
        s.x += v.x; s.y += v.y; s.z += v.z; s.w += v.w;
        s2.x += v.x * v.x; s2.y += v.y * v.y; s2.z += v.z * v.z; s2.w += v.w * v.w;
    }
    __shared__ float4 ls[256], ls2[256];
    __shared__ int lastflag;
    ls[threadIdx.x] = s;
    ls2[threadIdx.x] = s2;
    __syncthreads();
    if (rg == 0) {
        float4 ts = ls[cb], t2 = ls2[cb];
#pragma unroll
        for (int g = 1; g < 8; ++g) {
            float4 v = ls[g * 32 + cb], w = ls2[g * 32 + cb];
            ts.x += v.x; ts.y += v.y; ts.z += v.z; ts.w += v.w;
            t2.x += w.x; t2.y += w.y; t2.z += w.z; t2.w += w.w;
        }
        atomicAdd(&stats[cb * 4 + 0], ts.x);
        atomicAdd(&stats[cb * 4 + 1], ts.y);
        atomicAdd(&stats[cb * 4 + 2], ts.z);
        atomicAdd(&stats[cb * 4 + 3], ts.w);
        atomicAdd(&stats[128 + cb * 4 + 0], t2.x);
        atomicAdd(&stats[128 + cb * 4 + 1], t2.y);
        atomicAdd(&stats[128 + cb * 4 + 2], t2.z);
        atomicAdd(&stats[128 + cb * 4 + 3], t2.w);
    }
    __threadfence();
    __syncthreads();
    if (threadIdx.x == 0)
        lastflag = (atomicAdd(ticket, 1) == (int)gridDim.x - 1) ? 1 : 0;
    __syncthreads();
    if (lastflag && threadIdx.x < NHID) {
        int c = threadIdx.x;
        float sum = atomicAdd(&stats[c], 0.f);        // coherent read
        float sq  = atomicAdd(&stats[128 + c], 0.f);
        float mean = sum / (float)N_NODES;
        float var = fmaxf(sq / (float)N_NODES - mean * mean, 0.f);
        float inv = rsqrtf(var + BN_EPS);
        float sc = gamma[c] * inv;
        ss[c] = sc;
        ss[128 + c] = beta[c] - mean * sc;
    }
}

// ---------------- fused BN-apply + fc head ----------------

__global__ __launch_bounds__(256) void k_bnfc(float* __restrict__ embed,
                                              const float* __restrict__ ss,
                                              const float* __restrict__ fc_w,
                                              const float* __restrict__ fc_b,
                                              float* __restrict__ out) {
    __shared__ float se[64][68];
    __shared__ float sw[8][68];
    __shared__ float sb[8];
    const int tid = threadIdx.x;
    const int row0 = blockIdx.x * 64;
    {
        int d = tid;
        sw[d >> 6][d & 63] = fc_w[d];
        d = tid + 256;
        sw[d >> 6][d & 63] = fc_w[d];
        if (tid < 8) sb[tid] = fc_b[tid];
    }
    float4* ef4 = (float4*)embed;
    const float4* ssc4 = (const float4*)ss;
    const float4* ssh4 = (const float4*)(ss + 128);
#pragma unroll
    for (int i = 0; i < 8; ++i) {
        int d = tid + i * 256;     // 0..2047
        int r = d >> 5;            // row within block
        int cb = d & 31;           // float4 col
        int gr = row0 + r;
        if (gr < N_NODES) {
            float4 v = ef4[(size_t)gr * 32 + cb];
            float4 sc = ssc4[cb], sh = ssh4[cb];
            v.x = fmaf(v.x, sc.x, sh.x);
            v.y = fmaf(v.y, sc.y, sh.y);
            v.z = fmaf(v.z, sc.z, sh.z);
            v.w = fmaf(v.w, sc.w, sh.w);
            ef4[(size_t)gr * 32 + cb] = v;
            if (cb < 16) {
                se[r][cb * 4 + 0] = v.x; se[r][cb * 4 + 1] = v.y;
                se[r][cb * 4 + 2] = v.z; se[r][cb * 4 + 3] = v.w;
            }
        } else if (cb < 16) {
            se[r][cb * 4 + 0] = 0.f; se[r][cb * 4 + 1] = 0.f;
            se[r][cb * 4 + 2] = 0.f; se[r][cb * 4 + 3] = 0.f;
        }
    }
    __syncthreads();
    const int r = tid >> 2;
    const int j0 = (tid & 3) * 2;
    const int gr = row0 + r;
#pragma unroll
    for (int jj = 0; jj < 2; ++jj) {
        int j = j0 + jj;
        float s = sb[j];
#pragma unroll
        for (int k = 0; k < 64; ++k) s = fmaf(se[r][k], sw[j][k], s);
        if (gr < N_NODES) out[(size_t)gr * NCLASS + j] = s;
    }
}

// ---------------- launch ----------------

extern "C" void kernel_launch(void* const* d_in, const int* in_sizes, int n_in,
                              void* d_out, int out_size, void* d_ws, size_t ws_size,
                              hipStream_t stream) {
    const float* x     = (const float*)d_in[0];
    const int*   ei    = (const int*)d_in[1];
    const float* W     = (const float*)d_in[2];
    // d_in[3] = b_gc: cancels inside BatchNorm, unused.
    const float* gamma = (const float*)d_in[4];
    const float* beta  = (const float*)d_in[5];
    const float* fc_w  = (const float*)d_in[6];
    const float* fc_b  = (const float*)d_in[7];

    const int* src = ei;
    const int* dst = ei + N_EDGES;

    float* out   = (float*)d_out;
    float* embed = (float*)d_out + (size_t)N_NODES * NCLASS;  // agg lives here

    // workspace layout (~52 MB)
    char* ws = (char*)d_ws;
    size_t o = 0;
    unsigned* epack = (unsigned*)(ws + o);          o += (size_t)N_EDGES * 4;          // 12.8 MB
    unsigned short* hbS = (unsigned short*)(ws + o); o += (size_t)8 * PSTRIDE_U * 2;   // 25.6 MB planar
    o = (o + 255) & ~(size_t)255;
    int* esrc   = (int*)(ws + o);                   o += (size_t)N_EDGES * 4;          // 12.8 MB
    int* off    = (int*)(ws + o);                   o += (size_t)(N_NODES + 1) * 4;
    float* dinv = (float*)(ws + o);                 o += (size_t)N_NODES * 4;
    unsigned short* Wt = (unsigned short*)(ws + o); o += (size_t)NFEAT * NHID * 2;
    float* stats = (float*)(ws + o);                o += 256 * 4;
    float* ss    = (float*)(ws + o);                o += 256 * 4;
    int* ghist   = (int*)(ws + o);                  o += NBC * 4;
    int* coff    = (int*)(ws + o);                  o += (NBC + 1) * 4;
    int* ccur    = (int*)(ws + o);                  o += NBC * 4;
    int* ticket  = (int*)(ws + o);                  o += 4;

    hipMemsetAsync(ghist, 0, NBC * 4, stream);

    // two-level counting sort -> CSR (off, esrc) + dinv   (+fused Wt/zero-rows)
    k_chist<<<PART_BLOCKS + WT_BLOCKS, 256, 0, stream>>>(dst, ghist, W, Wt, hbS);
    k_cscan<<<1, 512, 0, stream>>>(ghist, coff, ccur, off, stats, ticket);
    k_part<<<PART_BLOCKS, 256, 0, stream>>>(src, dst, ccur, epack);
    k_fine<<<NBC, 256, 0, stream>>>(epack, coff, off, dinv, esrc);

    // hbS = planar bf16(dinv * (x @ W))
    k_gemm<<<(N_NODES + 63) / 64, 256, 0, stream>>>(x, Wt, dinv, hbS);

    // aggregation: 8 feature-slices pinned to XCDs via bid&7
    k_agg<<<8 * (N_NODES / 8), 512, 0, stream>>>(off, esrc, dinv, (const unsigned*)hbS, embed);

    // BatchNorm stats (+fused params in last block)
    k_stats<<<512, 256, 0, stream>>>(embed, stats, ticket, gamma, beta, ss);

    // BN apply + fc head
    k_bnfc<<<(N_NODES + 63) / 64, 256, 0, stream>>>(embed, ss, fc_w, fc_b, out);
}

// Round 9
// 314.290 us; speedup vs baseline: 1.5248x; 1.5248x over previous
//
#include <hip/hip_runtime.h>
#include <hip/hip_bf16.h>
#include <math.h>

#define N_NODES 100000
#define N_EDGES 3200000
#define NFEAT 128
#define NHID 128
#define NCLASS 8
#define BN_EPS 1e-5f
#define CB 512                       // coarse bucket = 512 nodes
#define NBC 196                      // ceil(100000/512)
#define EPB 8192                     // edges per k_part/k_chist block
#define PART_BLOCKS 391              // ceil(N_EDGES / EPB)
#define WT_BLOCKS 64                 // 16384 W elements / 256

typedef __attribute__((ext_vector_type(8))) short short8;
typedef __attribute__((ext_vector_type(4))) float f32x4;

__device__ __forceinline__ short f2bf(float f) {
    __hip_bfloat16 b = __float2bfloat16(f);   // RNE
    return *reinterpret_cast<short*>(&b);
}
__device__ __forceinline__ float bf_lo(unsigned u) { return __uint_as_float(u << 16); }
__device__ __forceinline__ float bf_hi(unsigned u) { return __uint_as_float(u & 0xffff0000u); }

// ---------------- coarse histogram (+ fused Wt convert & hb zero-row) ----------------

__global__ __launch_bounds__(256) void k_chist(const int* __restrict__ dst,
                                               int* __restrict__ ghist,
                                               const float* __restrict__ W,
                                               unsigned short* __restrict__ Wt,
                                               uint4* __restrict__ hbz) {
    if (blockIdx.x >= PART_BLOCKS) {
        int idx = (blockIdx.x - PART_BLOCKS) * 256 + threadIdx.x;
        if (idx < 16) hbz[idx] = (uint4){0u, 0u, 0u, 0u};   // 256 B zero row
        int k = idx >> 7, n = idx & 127;
        Wt[n * NFEAT + k] = (unsigned short)f2bf(W[idx]);
        return;
    }
    __shared__ int lh[NBC];
    const int tid = threadIdx.x;
    if (tid < NBC) lh[tid] = 0;
    __syncthreads();
    const int4* dst4 = (const int4*)dst;
    const int q0 = blockIdx.x * (EPB / 4) + tid;
#pragma unroll
    for (int i = 0; i < 8; ++i) {
        int q = q0 + i * 256;
        if (q < N_EDGES / 4) {
            int4 d = dst4[q];
            atomicAdd(&lh[d.x >> 9], 1);
            atomicAdd(&lh[d.y >> 9], 1);
            atomicAdd(&lh[d.z >> 9], 1);
            atomicAdd(&lh[d.w >> 9], 1);
        }
    }
    __syncthreads();
    if (tid < NBC) {
        int c = lh[tid];
        if (c) atomicAdd(&ghist[tid], c);
    }
}

// scan coarse hist; also zero BN stats + ticket
__global__ __launch_bounds__(512) void k_cscan(const int* __restrict__ ghist,
                                               int* __restrict__ coff,
                                               int* __restrict__ ccur,
                                               int* __restrict__ off,
                                               float* __restrict__ stats,
                                               int* __restrict__ ticket) {
    __shared__ int tmp[512];
    const int t = threadIdx.x;
    if (t < 256) stats[t] = 0.f;
    if (t == 0) *ticket = 0;
    int v = (t < NBC) ? ghist[t] : 0;
    tmp[t] = v;
    __syncthreads();
    for (int d = 1; d < 512; d <<= 1) {
        int u = (t >= d) ? tmp[t - d] : 0;
        __syncthreads();
        tmp[t] += u;
        __syncthreads();
    }
    int excl = tmp[t] - v;
    if (t < NBC) {
        coff[t] = excl;
        ccur[t] = excl;
    }
    if (t == NBC - 1) {
        coff[NBC] = tmp[t];
        off[N_NODES] = tmp[t];
    }
}

// ---------------- k_part: LDS-reordered counting-sort pass, coalesced writes ----------------
// packs (src<<9 | dst&511); 8192 edges/block reordered in LDS, streamed out.

__global__ __launch_bounds__(256) void k_part(const int* __restrict__ src,
                                              const int* __restrict__ dst,
                                              int* __restrict__ ccur,
                                              unsigned* __restrict__ epack) {
    __shared__ int lh[NBC];
    __shared__ int lstart[NBC];
    __shared__ int adj[NBC];
    __shared__ int stmp[256];
    __shared__ unsigned sorted[EPB];        // 32 KB
    __shared__ unsigned short bkt[EPB];     // 16 KB
    const int tid = threadIdx.x;
    if (tid < NBC) lh[tid] = 0;
    __syncthreads();
    const int4* src4 = (const int4*)src;
    const int4* dst4 = (const int4*)dst;
    const int q0 = blockIdx.x * (EPB / 4) + tid;
    int4 sv[8], dv[8];
    int rk[32];
#pragma unroll
    for (int i = 0; i < 8; ++i) {
        int q = q0 + i * 256;
        if (q < N_EDGES / 4) {
            sv[i] = src4[q];
            dv[i] = dst4[q];
            rk[i * 4 + 0] = atomicAdd(&lh[dv[i].x >> 9], 1);
            rk[i * 4 + 1] = atomicAdd(&lh[dv[i].y >> 9], 1);
            rk[i * 4 + 2] = atomicAdd(&lh[dv[i].z >> 9], 1);
            rk[i * 4 + 3] = atomicAdd(&lh[dv[i].w >> 9], 1);
        } else dv[i].x = -1;
    }
    __syncthreads();
    // scan lh (NBC<=256) with 256 threads
    int v = (tid < NBC) ? lh[tid] : 0;
    stmp[tid] = v;
    __syncthreads();
    for (int d = 1; d < 256; d <<= 1) {
        int u = (tid >= d) ? stmp[tid - d] : 0;
        __syncthreads();
        stmp[tid] += u;
        __syncthreads();
    }
    if (tid < NBC) {
        int ls = stmp[tid] - v;
        lstart[tid] = ls;
        adj[tid] = (v ? atomicAdd(&ccur[tid], v) : 0) - ls;
    }
    __syncthreads();
    // scatter into LDS bucket order
#pragma unroll
    for (int i = 0; i < 8; ++i) {
        if (dv[i].x >= 0) {
            int b, p;
            b = dv[i].x >> 9; p = lstart[b] + rk[i * 4 + 0];
            sorted[p] = ((unsigned)sv[i].x << 9) | (unsigned)(dv[i].x & 511); bkt[p] = (unsigned short)b;
            b = dv[i].y >> 9; p = lstart[b] + rk[i * 4 + 1];
            sorted[p] = ((unsigned)sv[i].y << 9) | (unsigned)(dv[i].y & 511); bkt[p] = (unsigned short)b;
            b = dv[i].z >> 9; p = lstart[b] + rk[i * 4 + 2];
            sorted[p] = ((unsigned)sv[i].z << 9) | (unsigned)(dv[i].z & 511); bkt[p] = (unsigned short)b;
            b = dv[i].w >> 9; p = lstart[b] + rk[i * 4 + 3];
            sorted[p] = ((unsigned)sv[i].w << 9) | (unsigned)(dv[i].w & 511); bkt[p] = (unsigned short)b;
        }
    }
    __syncthreads();
    const int vcnt = stmp[255];   // total valid edges this block
    for (int p = tid; p < vcnt; p += 256)
        epack[p + adj[bkt[p]]] = sorted[p];
}

// ---------------- per-coarse-bucket fine sort: exact CSR off/dinv/esrc ----------------

__global__ __launch_bounds__(256) void k_fine(const unsigned* __restrict__ epack,
                                              const int* __restrict__ coff,
                                              int* __restrict__ off,
                                              float* __restrict__ dinv,
                                              int* __restrict__ esrc) {
    __shared__ int lh[CB], lcur[CB], lsc[256];
    const int tid = threadIdx.x;
    const int b = blockIdx.x;
    const int node0 = b << 9;
    lh[tid] = 0;
    lh[tid + 256] = 0;
    __syncthreads();
    const int lo = coff[b], hiEnd = coff[b + 1];
    for (int i = lo + tid; i < hiEnd; i += 256)
        atomicAdd(&lh[epack[i] & 511u], 1);
    __syncthreads();
    // pairwise scan of 512 counters with 256 threads
    int v0 = lh[2 * tid], v1 = lh[2 * tid + 1];
    int s = v0 + v1;
    lsc[tid] = s;
    __syncthreads();
    for (int d = 1; d < 256; d <<= 1) {
        int u = (tid >= d) ? lsc[tid - d] : 0;
        __syncthreads();
        lsc[tid] += u;
        __syncthreads();
    }
    int pairExcl = lsc[tid] - s;
    lcur[2 * tid] = pairExcl;
    lcur[2 * tid + 1] = pairExcl + v0;
    int n0 = node0 + 2 * tid, n1 = n0 + 1;
    if (n0 < N_NODES) { off[n0] = lo + pairExcl;      dinv[n0] = rsqrtf((float)(v0 + 1)); }
    if (n1 < N_NODES) { off[n1] = lo + pairExcl + v0; dinv[n1] = rsqrtf((float)(v1 + 1)); }
    __syncthreads();
    for (int i = lo + tid; i < hiEnd; i += 256) {
        unsigned p = epack[i];
        int pos = atomicAdd(&lcur[p & 511u], 1);
        esrc[lo + pos] = (int)(p >> 9);
    }
}

// ---------------- MFMA GEMM: hb[r] = bf16(dinv[r] * (x @ W)[r]) ----------------

#define WSTRIDE 136
__global__ __launch_bounds__(256) void k_gemm(const float* __restrict__ x,
                                              const unsigned short* __restrict__ Wt,
                                              const float* __restrict__ dinv,
                                              unsigned short* __restrict__ hb) {
    __shared__ short wlds[NHID * WSTRIDE];
    const int tid = threadIdx.x;

    const unsigned* Wt32 = (const unsigned*)Wt;
    unsigned* wl32 = (unsigned*)wlds;
#pragma unroll
    for (int i = 0; i < 32; ++i) {
        int d = tid + i * 256;
        int n = d >> 6, kp = d & 63;
        wl32[n * (WSTRIDE / 2) + kp] = Wt32[d];
    }
    __syncthreads();

    const int wid = tid >> 6, lane = tid & 63;
    const int qw = lane >> 4, lr = lane & 15;
    const int arow = blockIdx.x * 64 + wid * 16 + lr;
    const bool avalid = arow < N_NODES;

    short8 a[4];
#pragma unroll
    for (int ks = 0; ks < 4; ++ks) {
        if (avalid) {
            const float* p = x + (size_t)arow * NFEAT + ks * 32 + qw * 8;
            float4 v0 = *(const float4*)p;
            float4 v1 = *(const float4*)(p + 4);
            short8 t;
            t[0] = f2bf(v0.x); t[1] = f2bf(v0.y); t[2] = f2bf(v0.z); t[3] = f2bf(v0.w);
            t[4] = f2bf(v1.x); t[5] = f2bf(v1.y); t[6] = f2bf(v1.z); t[7] = f2bf(v1.w);
            a[ks] = t;
        } else {
            short8 t;
#pragma unroll
            for (int j = 0; j < 8; ++j) t[j] = 0;
            a[ks] = t;
        }
    }

    f32x4 acc[8];
#pragma unroll
    for (int nt = 0; nt < 8; ++nt) acc[nt] = (f32x4){0.f, 0.f, 0.f, 0.f};

#pragma unroll
    for (int nt = 0; nt < 8; ++nt) {
#pragma unroll
        for (int ks = 0; ks < 4; ++ks) {
            short8 bfr = *(const short8*)&wlds[(nt * 16 + lr) * WSTRIDE + ks * 32 + qw * 8];
            acc[nt] = __builtin_amdgcn_mfma_f32_16x16x32_bf16(a[ks], bfr, acc[nt], 0, 0, 0);
        }
    }

    const int rbase = blockIdx.x * 64 + wid * 16 + qw * 4;
    float dv[4];
#pragma unroll
    for (int j = 0; j < 4; ++j) dv[j] = (rbase + j < N_NODES) ? dinv[rbase + j] : 0.f;
#pragma unroll
    for (int j = 0; j < 4; ++j) {
        int r = rbase + j;
        if (r >= N_NODES) continue;
#pragma unroll
        for (int nt = 0; nt < 8; ++nt)
            hb[(size_t)r * NHID + nt * 16 + lr] = (unsigned short)f2bf(dv[j] * acc[nt][j]);
    }
}

// ---------------- aggregation: 8 edges in flight per wave (round-6 version) ----------------

__global__ __launch_bounds__(256) void k_agg(const int* __restrict__ off,
                                             const int* __restrict__ esrc,
                                             const float* __restrict__ dinv,
                                             const uint2* __restrict__ hbq,
                                             float4* __restrict__ agg4) {
    const int node = (blockIdx.x << 2) | (threadIdx.x >> 6);
    const int lane = threadIdx.x & 63;
    const int hl = lane >> 5;
    const int cl = lane & 31;
    if (node >= N_NODES) return;

    const float dn = dinv[node];
    const int self = hl ? N_NODES : node;
    uint2 u0 = hbq[(size_t)self * 32 + cl];
    float aAx = bf_lo(u0.x), aAy = bf_hi(u0.x), aAz = bf_lo(u0.y), aAw = bf_hi(u0.y);
    float aBx = 0.f, aBy = 0.f, aBz = 0.f, aBw = 0.f;
    float aCx = 0.f, aCy = 0.f, aCz = 0.f, aCw = 0.f;
    float aDx = 0.f, aDy = 0.f, aDz = 0.f, aDw = 0.f;

    const int begin = off[node], end = off[node + 1];
    for (int base = begin; base < end; base += 64) {
        int m = end - base;
        if (m > 64) m = 64;
        int sv = (lane < m) ? esrc[base + lane] : N_NODES;
        const int kmax = (m + 7) >> 3;
        for (int k = 0; k < kmax; ++k) {
            int sA = __shfl(sv, 8 * k + 0 + hl);
            int sB = __shfl(sv, 8 * k + 2 + hl);
            int sC = __shfl(sv, 8 * k + 4 + hl);
            int sD = __shfl(sv, 8 * k + 6 + hl);
            uint2 uA = hbq[(size_t)sA * 32 + cl];
            uint2 uB = hbq[(size_t)sB * 32 + cl];
            uint2 uC = hbq[(size_t)sC * 32 + cl];
            uint2 uD = hbq[(size_t)sD * 32 + cl];
            aAx += bf_lo(uA.x); aAy += bf_hi(uA.x); aAz += bf_lo(uA.y); aAw += bf_hi(uA.y);
            aBx += bf_lo(uB.x); aBy += bf_hi(uB.x); aBz += bf_lo(uB.y); aBw += bf_hi(uB.y);
            aCx += bf_lo(uC.x); aCy += bf_hi(uC.x); aCz += bf_lo(uC.y); aCw += bf_hi(uC.y);
            aDx += bf_lo(uD.x); aDy += bf_hi(uD.x); aDz += bf_lo(uD.y); aDw += bf_hi(uD.y);
        }
    }
    float ax = (aAx + aBx) + (aCx + aDx);
    float ay = (aAy + aBy) + (aCy + aDy);
    float az = (aAz + aBz) + (aCz + aDz);
    float aw = (aAw + aBw) + (aCw + aDw);
    ax += __shfl_xor(ax, 32);
    ay += __shfl_xor(ay, 32);
    az += __shfl_xor(az, 32);
    aw += __shfl_xor(aw, 32);
    if (hl == 0) {
        float4 o;
        o.x = ax * dn; o.y = ay * dn; o.z = az * dn; o.w = aw * dn;
        agg4[(size_t)node * 32 + cl] = o;
    }
}

// ---------------- BatchNorm stats + (last block) params ----------------

__global__ __launch_bounds__(256) void k_stats(const float* __restrict__ agg,
                                               float* __restrict__ stats,
                                               int* __restrict__ ticket,
                                               const float* __restrict__ gamma,
                                               const float* __restrict__ beta,
                                               float* __restrict__ ss) {
    const int cb = threadIdx.x & 31;
    const int rg = threadIdx.x >> 5;
    const float4* a4 = (const float4*)agg;
    float4 s = {0.f, 0.f, 0.f, 0.f}, s2 = {0.f, 0.f, 0.f, 0.f};
    for (int r = blockIdx.x * 8 + rg; r < N_NODES; r += gridDim.x * 8) {
        float4 v = a4[(size_t)r * 32 + cb];
        s.x += v.x; s.y += v.y; s.z += v.z; s.w += v.w;
        s2.x += v.x * v.x; s2.y += v.y * v.y; s2.z += v.z * v.z; s2.w += v.w * v.w;
    }
    __shared__ float4 ls[256], ls2[256];
    __shared__ int lastflag;
    ls[threadIdx.x] = s;
    ls2[threadIdx.x] = s2;
    __syncthreads();
    if (rg == 0) {
        float4 ts = ls[cb], t2 = ls2[cb];
#pragma unroll
        for (int g = 1; g < 8; ++g) {
            float4 v = ls[g * 32 + cb], w = ls2[g * 32 + cb];
            ts.x += v.x; ts.y += v.y; ts.z += v.z; ts.w += v.w;
            t2.x += w.x; t2.y += w.y; t2.z += w.z; t2.w += w.w;
        }
        atomicAdd(&stats[cb * 4 + 0], ts.x);
        atomicAdd(&stats[cb * 4 + 1], ts.y);
        atomicAdd(&stats[cb * 4 + 2], ts.z);
        atomicAdd(&stats[cb * 4 + 3], ts.w);
        atomicAdd(&stats[128 + cb * 4 + 0], t2.x);
        atomicAdd(&stats[128 + cb * 4 + 1], t2.y);
        atomicAdd(&stats[128 + cb * 4 + 2], t2.z);
        atomicAdd(&stats[128 + cb * 4 + 3], t2.w);
    }
    __threadfence();
    __syncthreads();
    if (threadIdx.x == 0)
        lastflag = (atomicAdd(ticket, 1) == (int)gridDim.x - 1) ? 1 : 0;
    __syncthreads();
    if (lastflag && threadIdx.x < NHID) {
        int c = threadIdx.x;
        float sum = atomicAdd(&stats[c], 0.f);
        float sq  = atomicAdd(&stats[128 + c], 0.f);
        float mean = sum / (float)N_NODES;
        float var = fmaxf(sq / (float)N_NODES - mean * mean, 0.f);
        float inv = rsqrtf(var + BN_EPS);
        float sc = gamma[c] * inv;
        ss[c] = sc;
        ss[128 + c] = beta[c] - mean * sc;
    }
}

// ---------------- fused BN-apply + fc head ----------------

__global__ __launch_bounds__(256) void k_bnfc(float* __restrict__ embed,
                                              const float* __restrict__ ss,
                                              const float* __restrict__ fc_w,
                                              const float* __restrict__ fc_b,
                                              float* __restrict__ out) {
    __shared__ float se[64][68];
    __shared__ float sw[8][68];
    __shared__ float sb[8];
    const int tid = threadIdx.x;
    const int row0 = blockIdx.x * 64;
    {
        int d = tid;
        sw[d >> 6][d & 63] = fc_w[d];
        d = tid + 256;
        sw[d >> 6][d & 63] = fc_w[d];
        if (tid < 8) sb[tid] = fc_b[tid];
    }
    float4* ef4 = (float4*)embed;
    const float4* ssc4 = (const float4*)ss;
    const float4* ssh4 = (const float4*)(ss + 128);
#pragma unroll
    for (int i = 0; i < 8; ++i) {
        int d = tid + i * 256;
        int r = d >> 5;
        int cb = d & 31;
        int gr = row0 + r;
        if (gr < N_NODES) {
            float4 v = ef4[(size_t)gr * 32 + cb];
            float4 sc = ssc4[cb], sh = ssh4[cb];
            v.x = fmaf(v.x, sc.x, sh.x);
            v.y = fmaf(v.y, sc.y, sh.y);
            v.z = fmaf(v.z, sc.z, sh.z);
            v.w = fmaf(v.w, sc.w, sh.w);
            ef4[(size_t)gr * 32 + cb] = v;
            if (cb < 16) {
                se[r][cb * 4 + 0] = v.x; se[r][cb * 4 + 1] = v.y;
                se[r][cb * 4 + 2] = v.z; se[r][cb * 4 + 3] = v.w;
            }
        } else if (cb < 16) {
            se[r][cb * 4 + 0] = 0.f; se[r][cb * 4 + 1] = 0.f;
            se[r][cb * 4 + 2] = 0.f; se[r][cb * 4 + 3] = 0.f;
        }
    }
    __syncthreads();
    const int r = tid >> 2;
    const int j0 = (tid & 3) * 2;
    const int gr = row0 + r;
#pragma unroll
    for (int jj = 0; jj < 2; ++jj) {
        int j = j0 + jj;
        float s = sb[j];
#pragma unroll
        for (int k = 0; k < 64; ++k) s = fmaf(se[r][k], sw[j][k], s);
        if (gr < N_NODES) out[(size_t)gr * NCLASS + j] = s;
    }
}

// ---------------- launch ----------------

extern "C" void kernel_launch(void* const* d_in, const int* in_sizes, int n_in,
                              void* d_out, int out_size, void* d_ws, size_t ws_size,
                              hipStream_t stream) {
    const float* x     = (const float*)d_in[0];
    const int*   ei    = (const int*)d_in[1];
    const float* W     = (const float*)d_in[2];
    // d_in[3] = b_gc: cancels inside BatchNorm, unused.
    const float* gamma = (const float*)d_in[4];
    const float* beta  = (const float*)d_in[5];
    const float* fc_w  = (const float*)d_in[6];
    const float* fc_b  = (const float*)d_in[7];

    const int* src = ei;
    const int* dst = ei + N_EDGES;

    float* out   = (float*)d_out;
    float* embed = (float*)d_out + (size_t)N_NODES * NCLASS;  // agg lives here

    // workspace layout (~52 MB)
    char* ws = (char*)d_ws;
    size_t o = 0;
    unsigned* epack = (unsigned*)(ws + o);          o += (size_t)N_EDGES * 4;               // 12.8 MB
    unsigned short* hb = (unsigned short*)(ws + o); o += (size_t)(N_NODES + 1) * NHID * 2;  // 25.6 MB + zero row
    o = (o + 255) & ~(size_t)255;
    int* esrc   = (int*)(ws + o);                   o += (size_t)N_EDGES * 4;               // 12.8 MB
    int* off    = (int*)(ws + o);                   o += (size_t)(N_NODES + 1) * 4;
    float* dinv = (float*)(ws + o);                 o += (size_t)N_NODES * 4;
    unsigned short* Wt = (unsigned short*)(ws + o); o += (size_t)NFEAT * NHID * 2;
    float* stats = (float*)(ws + o);                o += 256 * 4;
    float* ss    = (float*)(ws + o);                o += 256 * 4;
    int* ghist   = (int*)(ws + o);                  o += NBC * 4;
    int* coff    = (int*)(ws + o);                  o += (NBC + 1) * 4;
    int* ccur    = (int*)(ws + o);                  o += NBC * 4;
    int* ticket  = (int*)(ws + o);                  o += 4;

    hipMemsetAsync(ghist, 0, NBC * 4, stream);

    // two-level counting sort -> CSR (off, esrc) + dinv   (+fused Wt/zero-row)
    k_chist<<<PART_BLOCKS + WT_BLOCKS, 256, 0, stream>>>(dst, ghist, W, Wt,
                                                         (uint4*)(hb + (size_t)N_NODES * NHID));
    k_cscan<<<1, 512, 0, stream>>>(ghist, coff, ccur, off, stats, ticket);
    k_part<<<PART_BLOCKS, 256, 0, stream>>>(src, dst, ccur, epack);
    k_fine<<<NBC, 256, 0, stream>>>(epack, coff, off, dinv, esrc);

    // hb = bf16(dinv * (x @ W))
    k_gemm<<<(N_NODES + 63) / 64, 256, 0, stream>>>(x, Wt, dinv, hb);

    // aggregation
    k_agg<<<(N_NODES + 3) / 4, 256, 0, stream>>>(off, esrc, dinv, (const uint2*)hb, (float4*)embed);

    // BatchNorm stats (+fused params in last block)
    k_stats<<<512, 256, 0, stream>>>(embed, stats, ticket, gamma, beta, ss);

    // BN apply + fc head
    k_bnfc<<<(N_NODES + 63) / 64, 256, 0, stream>>>(embed, ss, fc_w, fc_b, out);
}